// Round 5
// baseline (466.365 us; speedup 1.0000x reference)
//
#include <hip/hip_runtime.h>
#include <hip/hip_fp16.h>

#define VOX (128 * 128 * 128)   // 2097152
#define P 130                   // padded dim
#define PP (P * P)              // 16900
#define PVOX (P * P * P)        // 2197000

typedef unsigned short u16;
typedef _Float16 f16x2 __attribute__((ext_vector_type(2)));
typedef _Float16 f16x8 __attribute__((ext_vector_type(8)));
typedef __attribute__((ext_vector_type(4))) float f32x4;
typedef __attribute__((ext_vector_type(2))) float f32x2;

__device__ __forceinline__ u16 f2h(float f) {
    return __builtin_bit_cast(unsigned short, (_Float16)f);
}
__device__ __forceinline__ unsigned pkh_relu(float a, float b) {
    float ra = a > 0.f ? a : 0.f, rb = b > 0.f ? b : 0.f;
    return (unsigned)f2h(ra) | ((unsigned)f2h(rb) << 16);
}
__device__ __forceinline__ f16x2 h2(unsigned u) { return __builtin_bit_cast(f16x2, u); }

// dot2: acc += a.x*b.x + a.y*b.y  (f32 accumulate, single V_DOT2_F32_F16)
__device__ __forceinline__ float dot2(unsigned a, unsigned b, float c) {
#if __has_builtin(__builtin_amdgcn_fdot2)
    return __builtin_amdgcn_fdot2(h2(a), h2(b), c, false);
#else
    f16x2 av = h2(a), bv = h2(b);
    c = fmaf((float)av.x, (float)bv.x, c);
    return fmaf((float)av.y, (float)bv.y, c);
#endif
}

// fast tanh: 1 - 2/(1+e^{2x})
__device__ __forceinline__ float fast_tanh(float x) {
    float e = __expf(2.0f * x);
    return 1.0f - 2.0f * __builtin_amdgcn_rcpf(1.0f + e);
}

// prep: w2frag[(s*64+lane)*8+j] = f16(w2[oc=lane&15][ic=j][tap=s*4+(lane>>4)]), 0 if tap>26
//       w3p[tap*8+j]  = packed f16 pair (w3[2j][tap], w3[2j+1][tap])
//       w1p[tap*4+j]  = float2 (w1[2j][tap], w1[2j+1][tap])
__global__ __launch_bounds__(256) void prep_kernel(
    const float* __restrict__ w1, const float* __restrict__ w2,
    const float* __restrict__ w3, u16* __restrict__ w2frag,
    unsigned* __restrict__ w3p, float2* __restrict__ w1p) {
    int i = blockIdx.x * 256 + threadIdx.x;
    if (i < 3584) {
        int j = i & 7, l = (i >> 3) & 63, s = i >> 9;
        int tap = s * 4 + (l >> 4), oc = l & 15, ic = j;
        float v = (tap < 27) ? w2[(oc * 8 + ic) * 27 + tap] : 0.0f;
        w2frag[i] = f2h(v);
    }
    if (i < 216) {
        int tap = i >> 3, j = i & 7;
        w3p[i] = (unsigned)f2h(w3[(2 * j) * 27 + tap]) |
                 ((unsigned)f2h(w3[(2 * j + 1) * 27 + tap]) << 16);
    }
    if (i < 108) {
        int tap = i >> 2, j = i & 3;
        w1p[i] = make_float2(w1[(2 * j) * 27 + tap], w1[(2 * j + 1) * 27 + tap]);
    }
}

// zero the halo shells of padded x1 (8ch) and x2 (16ch)
__global__ __launch_bounds__(256) void zero_halo_kernel(u16* __restrict__ x1,
                                                        u16* __restrict__ x2) {
    int i = blockIdx.x * 256 + threadIdx.x;
    if (i >= PVOX) return;
    int d = i / PP;
    int r = i - d * PP;
    int h = r / P;
    int w = r - h * P;
    if (d == 0 || d == P - 1 || h == 0 || h == P - 1 || w == 0 || w == P - 1) {
        uint4 z = {0u, 0u, 0u, 0u};
        *(uint4*)(x1 + (size_t)i * 8) = z;
        *(uint4*)(x2 + (size_t)i * 16) = z;
        *(uint4*)(x2 + (size_t)i * 16 + 8) = z;
    }
}

// conv1: in [128^3] fp32 (one batch), field fused, relu, out f16 channels-last padded [130^3][8]
// 2 voxels/thread; packed f32x2 channel-pair accumulators (v_pk_fma_f32).
__global__ __launch_bounds__(256, 4) void conv1_kernel(
    const float* __restrict__ in, const float2* __restrict__ w1p,
    const float* __restrict__ b1, u16* __restrict__ x1) {
    __shared__ float table[384];
    for (int s = threadIdx.x; s < 384; s += 256)
        table[s] = 1.0f + 0.1f * sinf(6.283185307179586f * (float)s / 384.0f);
    __syncthreads();

    const int t = blockIdx.x * 256 + threadIdx.x;  // VOX/2 threads
    const int w0 = (t & 63) * 2;
    const int h = (t >> 6) & 127;
    const int d = t >> 13;

    f32x2 acc0[4], acc1[4];
#pragma unroll
    for (int j = 0; j < 4; ++j) {
        f32x2 b = {b1[2 * j], b1[2 * j + 1]};
        acc0[j] = b;
        acc1[j] = b;
    }

#pragma unroll
    for (int dz = 0; dz < 3; ++dz) {
        const int zz = d + dz - 1;
        const int zc = zz < 0 ? 0 : (zz > 127 ? 127 : zz);
        const bool zok = (unsigned)zz < 128u;
#pragma unroll
        for (int dy = 0; dy < 3; ++dy) {
            const int yy = h + dy - 1;
            const int yc = yy < 0 ? 0 : (yy > 127 ? 127 : yy);
            const bool rok = zok && ((unsigned)yy < 128u);
            const int rowbase = (zc * 128 + yc) * 128;
            const int sbase = zz + yy;
            float val[4];
#pragma unroll
            for (int i = 0; i < 4; ++i) {
                const int xa = w0 - 1 + i;
                const int xc = xa < 0 ? 0 : (xa > 127 ? 127 : xa);
                int si = sbase + xa;
                si = si < 0 ? 0 : (si > 381 ? 381 : si);
                const float m = (rok && ((unsigned)xa < 128u)) ? table[si] : 0.0f;
                val[i] = in[rowbase + xc] * m;
            }
#pragma unroll
            for (int dx = 0; dx < 3; ++dx) {
                const int tap = dz * 9 + dy * 3 + dx;
#pragma unroll
                for (int j = 0; j < 4; ++j) {
                    const float2 wraw = w1p[tap * 4 + j];
                    const f32x2 wv = {wraw.x, wraw.y};
                    acc0[j] = __builtin_elementwise_fma(wv, (f32x2){val[dx], val[dx]}, acc0[j]);
                    acc1[j] = __builtin_elementwise_fma(wv, (f32x2){val[dx + 1], val[dx + 1]}, acc1[j]);
                }
            }
        }
    }
    const size_t elem = ((size_t)(d + 1) * P + (h + 1)) * P + (w0 + 1);
    uint4 o0, o1;
    o0.x = pkh_relu(acc0[0].x, acc0[0].y); o0.y = pkh_relu(acc0[1].x, acc0[1].y);
    o0.z = pkh_relu(acc0[2].x, acc0[2].y); o0.w = pkh_relu(acc0[3].x, acc0[3].y);
    o1.x = pkh_relu(acc1[0].x, acc1[0].y); o1.y = pkh_relu(acc1[1].x, acc1[1].y);
    o1.z = pkh_relu(acc1[2].x, acc1[2].y); o1.w = pkh_relu(acc1[3].x, acc1[3].y);
    *(uint4*)(x1 + elem * 8) = o0;
    *(uint4*)(x1 + (elem + 1) * 8) = o1;
}

// conv2: implicit-GEMM MFMA (f16), padded layouts, no boundary logic.
// One wave = one (d,h) row = 8 tiles of 16 voxels; 7 k-steps; 56 MFMAs/wave.
// B-frags hoisted; 128-VGPR budget lets A loads batch ahead of MFMAs.
__global__ __launch_bounds__(256, 4) void conv2_mfma_kernel(
    const u16* __restrict__ x1, const u16* __restrict__ w2frag,
    const float* __restrict__ b2, u16* __restrict__ x2) {
    const int lane = threadIdx.x & 63;
    const int row = blockIdx.x * 4 + (threadIdx.x >> 6);
    const int q = lane >> 4;
    const int mi = lane & 15;
    const int d0 = row >> 7;
    const int h0 = row & 127;

    f16x8 bf[7];
#pragma unroll
    for (int s = 0; s < 7; ++s)
        bf[s] = *(const f16x8*)(w2frag + (size_t)(s * 64 + lane) * 8);

    f32x4 acc[8];
#pragma unroll
    for (int t = 0; t < 8; ++t) acc[t] = (f32x4){0.f, 0.f, 0.f, 0.f};

#pragma unroll
    for (int s = 0; s < 7; ++s) {
        int tap = s * 4 + q;
        if (tap > 26) tap = 26;  // pad tap: B-frag is zero there
        const int dz = tap / 9;
        const int rem = tap - dz * 9;
        const int dy = rem / 3;
        const int dx = rem - dy * 3;
        const u16* ap = x1 + ((size_t)((d0 + dz) * P + (h0 + dy)) * P + (mi + dx)) * 8;
        f16x8 a[8];
#pragma unroll
        for (int t = 0; t < 8; ++t) a[t] = *(const f16x8*)(ap + t * 128);
#pragma unroll
        for (int t = 0; t < 8; ++t)
            acc[t] = __builtin_amdgcn_mfma_f32_16x16x32_f16(a[t], bf[s], acc[t], 0, 0, 0);
    }

    // C/D: col(oc)=mi, row(m)=q*4+r -> voxel w = 16t + q*4 + r
    const float bias = b2[mi];
    const size_t obase = ((size_t)(d0 + 1) * P + (h0 + 1)) * P + 1;
#pragma unroll
    for (int t = 0; t < 8; ++t) {
#pragma unroll
        for (int r = 0; r < 4; ++r) {
            float v = acc[t][r] + bias;
            v = v > 0.f ? v : 0.f;
            x2[(obase + 16 * t + q * 4 + r) * 16 + mi] = f2h(v);
        }
    }
}

// conv3: padded x2 [130^3][16] f16 -> out fp32 [128^3] (one batch), tanh.
// 4 voxels/thread: per (dz,dy) row, 6 chunk-loads (12 x b128) shared across
// 3 dx taps and 4 voxels; 96 fdot2 per row. Needs ~80 VGPR -> launch_bounds(256,4).
__global__ __launch_bounds__(256, 4) void conv3_kernel(
    const u16* __restrict__ x2, const unsigned* __restrict__ w3p,
    const float* __restrict__ b3, float* __restrict__ out) {
    const int t = blockIdx.x * 256 + threadIdx.x;  // VOX/4 threads
    const int w0 = (t & 31) * 4;
    const int h = (t >> 5) & 127;
    const int d = t >> 12;

    float a0[4] = {0.f, 0.f, 0.f, 0.f};
    float a1[4] = {0.f, 0.f, 0.f, 0.f};

#pragma unroll
    for (int dz = 0; dz < 3; ++dz) {
#pragma unroll
        for (int dy = 0; dy < 3; ++dy) {
            // chunk c covers padded w index w0+c == unpadded voxel w0-1+c
            const u16* rp = x2 + ((size_t)((d + dz) * P + (h + dy)) * P + w0) * 16;
            uint4 lo[6], hi[6];
#pragma unroll
            for (int c = 0; c < 6; ++c) {
                lo[c] = *(const uint4*)(rp + c * 16);
                hi[c] = *(const uint4*)(rp + c * 16 + 8);
            }
            const unsigned* wp = w3p + (dz * 9 + dy * 3) * 8;
#pragma unroll
            for (int dx = 0; dx < 3; ++dx) {
#pragma unroll
                for (int v = 0; v < 4; ++v) {
                    const int c = v + dx;
                    a0[v] = dot2(lo[c].x, wp[dx * 8 + 0], a0[v]);
                    a1[v] = dot2(lo[c].y, wp[dx * 8 + 1], a1[v]);
                    a0[v] = dot2(lo[c].z, wp[dx * 8 + 2], a0[v]);
                    a1[v] = dot2(lo[c].w, wp[dx * 8 + 3], a1[v]);
                    a0[v] = dot2(hi[c].x, wp[dx * 8 + 4], a0[v]);
                    a1[v] = dot2(hi[c].y, wp[dx * 8 + 5], a1[v]);
                    a0[v] = dot2(hi[c].z, wp[dx * 8 + 6], a0[v]);
                    a1[v] = dot2(hi[c].w, wp[dx * 8 + 7], a1[v]);
                }
            }
        }
    }
    const float bias = b3[0];
    float4 o;
    o.x = fast_tanh(a0[0] + a1[0] + bias);
    o.y = fast_tanh(a0[1] + a1[1] + bias);
    o.z = fast_tanh(a0[2] + a1[2] + bias);
    o.w = fast_tanh(a0[3] + a1[3] + bias);
    *(float4*)(out + ((size_t)(d * 128 + h) * 128 + w0)) = o;
}

extern "C" void kernel_launch(void* const* d_in, const int* in_sizes, int n_in,
                              void* d_out, int out_size, void* d_ws, size_t ws_size,
                              hipStream_t stream) {
    const float* cube = (const float*)d_in[0];
    const float* w1 = (const float*)d_in[1];
    const float* b1 = (const float*)d_in[2];
    const float* w2 = (const float*)d_in[3];
    const float* b2 = (const float*)d_in[4];
    const float* w3 = (const float*)d_in[5];
    const float* b3 = (const float*)d_in[6];
    float* out = (float*)d_out;

    // ws: w2frag 7168B | w3p 864B @7168 | w1p 864B @8032 | x1 @16384 | x2
    char* ws = (char*)d_ws;
    u16* w2frag = (u16*)ws;
    unsigned* w3p = (unsigned*)(ws + 7168);
    float2* w1p = (float2*)(ws + 8032);
    u16* x1 = (u16*)(ws + 16384);
    u16* x2 = (u16*)(ws + 16384 + (size_t)PVOX * 8 * sizeof(u16));

    prep_kernel<<<dim3(14), dim3(256), 0, stream>>>(w1, w2, w3, w2frag, w3p, w1p);
    zero_halo_kernel<<<dim3((PVOX + 255) / 256), dim3(256), 0, stream>>>(x1, x2);

    for (int b = 0; b < 2; ++b) {
        conv1_kernel<<<dim3(VOX / 2 / 256), dim3(256), 0, stream>>>(
            cube + (size_t)b * VOX, w1p, b1, x1);
        conv2_mfma_kernel<<<dim3(128 * 128 / 4), dim3(256), 0, stream>>>(x1, w2frag, b2, x2);
        conv3_kernel<<<dim3(VOX / 4 / 256), dim3(256), 0, stream>>>(
            x2, w3p, b3, out + (size_t)b * VOX);
    }
}

// Round 6
// 323.143 us; speedup vs baseline: 1.4432x; 1.4432x over previous
//
#include <hip/hip_runtime.h>
#include <hip/hip_fp16.h>

#define VOX (128 * 128 * 128)   // 2097152
#define P 130                   // padded dim
#define PP (P * P)              // 16900
#define PVOX (P * P * P)        // 2197000

typedef unsigned short u16;
typedef _Float16 f16x2 __attribute__((ext_vector_type(2)));
typedef _Float16 f16x8 __attribute__((ext_vector_type(8)));
typedef __attribute__((ext_vector_type(4))) float f32x4;
typedef __attribute__((ext_vector_type(2))) float f32x2;

__device__ __forceinline__ u16 f2h(float f) {
    return __builtin_bit_cast(unsigned short, (_Float16)f);
}
__device__ __forceinline__ unsigned pkh_relu(float a, float b) {
    float ra = a > 0.f ? a : 0.f, rb = b > 0.f ? b : 0.f;
    return (unsigned)f2h(ra) | ((unsigned)f2h(rb) << 16);
}
__device__ __forceinline__ f16x2 h2(unsigned u) { return __builtin_bit_cast(f16x2, u); }

// dot2: acc += a.x*b.x + a.y*b.y  (f32 accumulate, single V_DOT2_F32_F16)
__device__ __forceinline__ float dot2(unsigned a, unsigned b, float c) {
#if __has_builtin(__builtin_amdgcn_fdot2)
    return __builtin_amdgcn_fdot2(h2(a), h2(b), c, false);
#else
    f16x2 av = h2(a), bv = h2(b);
    c = fmaf((float)av.x, (float)bv.x, c);
    return fmaf((float)av.y, (float)bv.y, c);
#endif
}

// fast tanh: 1 - 2/(1+e^{2x})
__device__ __forceinline__ float fast_tanh(float x) {
    float e = __expf(2.0f * x);
    return 1.0f - 2.0f * __builtin_amdgcn_rcpf(1.0f + e);
}

// prep: w2frag[(s*64+lane)*8+j] = f16(w2[oc=lane&15][ic=j][tap=s*4+(lane>>4)]), 0 if tap>26
//       w3p[tap*8+j]  = packed f16 pair (w3[2j][tap], w3[2j+1][tap])
//       w1p[tap*4+j]  = float2 (w1[2j][tap], w1[2j+1][tap])
__global__ __launch_bounds__(256) void prep_kernel(
    const float* __restrict__ w1, const float* __restrict__ w2,
    const float* __restrict__ w3, u16* __restrict__ w2frag,
    unsigned* __restrict__ w3p, float2* __restrict__ w1p) {
    int i = blockIdx.x * 256 + threadIdx.x;
    if (i < 3584) {
        int j = i & 7, l = (i >> 3) & 63, s = i >> 9;
        int tap = s * 4 + (l >> 4), oc = l & 15, ic = j;
        float v = (tap < 27) ? w2[(oc * 8 + ic) * 27 + tap] : 0.0f;
        w2frag[i] = f2h(v);
    }
    if (i < 216) {
        int tap = i >> 3, j = i & 7;
        w3p[i] = (unsigned)f2h(w3[(2 * j) * 27 + tap]) |
                 ((unsigned)f2h(w3[(2 * j + 1) * 27 + tap]) << 16);
    }
    if (i < 108) {
        int tap = i >> 2, j = i & 3;
        w1p[i] = make_float2(w1[(2 * j) * 27 + tap], w1[(2 * j + 1) * 27 + tap]);
    }
}

// zero the halo shells of padded x1 (8ch) and x2 (16ch)
__global__ __launch_bounds__(256) void zero_halo_kernel(u16* __restrict__ x1,
                                                        u16* __restrict__ x2) {
    int i = blockIdx.x * 256 + threadIdx.x;
    if (i >= PVOX) return;
    int d = i / PP;
    int r = i - d * PP;
    int h = r / P;
    int w = r - h * P;
    if (d == 0 || d == P - 1 || h == 0 || h == P - 1 || w == 0 || w == P - 1) {
        uint4 z = {0u, 0u, 0u, 0u};
        *(uint4*)(x1 + (size_t)i * 8) = z;
        *(uint4*)(x2 + (size_t)i * 16) = z;
        *(uint4*)(x2 + (size_t)i * 16 + 8) = z;
    }
}

// conv1: in [128^3] fp32 (one batch), field fused, relu, out f16 channels-last padded [130^3][8]
// 2 voxels/thread; packed f32x2 channel-pair accumulators (v_pk_fma_f32).
__global__ __launch_bounds__(256) void conv1_kernel(
    const float* __restrict__ in, const float2* __restrict__ w1p,
    const float* __restrict__ b1, u16* __restrict__ x1) {
    __shared__ float table[384];
    for (int s = threadIdx.x; s < 384; s += 256)
        table[s] = 1.0f + 0.1f * sinf(6.283185307179586f * (float)s / 384.0f);
    __syncthreads();

    const int t = blockIdx.x * 256 + threadIdx.x;  // VOX/2 threads
    const int w0 = (t & 63) * 2;
    const int h = (t >> 6) & 127;
    const int d = t >> 13;

    f32x2 acc0[4], acc1[4];
#pragma unroll
    for (int j = 0; j < 4; ++j) {
        f32x2 b = {b1[2 * j], b1[2 * j + 1]};
        acc0[j] = b;
        acc1[j] = b;
    }

#pragma unroll
    for (int dz = 0; dz < 3; ++dz) {
        const int zz = d + dz - 1;
        const int zc = zz < 0 ? 0 : (zz > 127 ? 127 : zz);
        const bool zok = (unsigned)zz < 128u;
#pragma unroll
        for (int dy = 0; dy < 3; ++dy) {
            const int yy = h + dy - 1;
            const int yc = yy < 0 ? 0 : (yy > 127 ? 127 : yy);
            const bool rok = zok && ((unsigned)yy < 128u);
            const int rowbase = (zc * 128 + yc) * 128;
            const int sbase = zz + yy;
            float val[4];
#pragma unroll
            for (int i = 0; i < 4; ++i) {
                const int xa = w0 - 1 + i;
                const int xc = xa < 0 ? 0 : (xa > 127 ? 127 : xa);
                int si = sbase + xa;
                si = si < 0 ? 0 : (si > 381 ? 381 : si);
                const float m = (rok && ((unsigned)xa < 128u)) ? table[si] : 0.0f;
                val[i] = in[rowbase + xc] * m;
            }
#pragma unroll
            for (int dx = 0; dx < 3; ++dx) {
                const int tap = dz * 9 + dy * 3 + dx;
#pragma unroll
                for (int j = 0; j < 4; ++j) {
                    const float2 wraw = w1p[tap * 4 + j];
                    const f32x2 wv = {wraw.x, wraw.y};
                    acc0[j] = __builtin_elementwise_fma(wv, (f32x2){val[dx], val[dx]}, acc0[j]);
                    acc1[j] = __builtin_elementwise_fma(wv, (f32x2){val[dx + 1], val[dx + 1]}, acc1[j]);
                }
            }
        }
    }
    const size_t elem = ((size_t)(d + 1) * P + (h + 1)) * P + (w0 + 1);
    uint4 o0, o1;
    o0.x = pkh_relu(acc0[0].x, acc0[0].y); o0.y = pkh_relu(acc0[1].x, acc0[1].y);
    o0.z = pkh_relu(acc0[2].x, acc0[2].y); o0.w = pkh_relu(acc0[3].x, acc0[3].y);
    o1.x = pkh_relu(acc1[0].x, acc1[0].y); o1.y = pkh_relu(acc1[1].x, acc1[1].y);
    o1.z = pkh_relu(acc1[2].x, acc1[2].y); o1.w = pkh_relu(acc1[3].x, acc1[3].y);
    *(uint4*)(x1 + elem * 8) = o0;
    *(uint4*)(x1 + (elem + 1) * 8) = o1;
}

// conv2: implicit-GEMM MFMA (f16), padded layouts, no boundary logic.
// One wave = one (d,h) row = 8 tiles of 16 voxels; 7 k-steps; 56 MFMAs/wave.
// (round-4 form: per-tile immediate consumption, default reg budget)
__global__ __launch_bounds__(256) void conv2_mfma_kernel(
    const u16* __restrict__ x1, const u16* __restrict__ w2frag,
    const float* __restrict__ b2, u16* __restrict__ x2) {
    const int lane = threadIdx.x & 63;
    const int row = blockIdx.x * 4 + (threadIdx.x >> 6);
    const int q = lane >> 4;
    const int mi = lane & 15;
    const int d0 = row >> 7;
    const int h0 = row & 127;

    f32x4 acc[8];
#pragma unroll
    for (int t = 0; t < 8; ++t) acc[t] = (f32x4){0.f, 0.f, 0.f, 0.f};

#pragma unroll
    for (int s = 0; s < 7; ++s) {
        int tap = s * 4 + q;
        if (tap > 26) tap = 26;  // pad tap: B-frag is zero there
        const int dz = tap / 9;
        const int rem = tap - dz * 9;
        const int dy = rem / 3;
        const int dx = rem - dy * 3;
        const u16* ap = x1 + ((size_t)((d0 + dz) * P + (h0 + dy)) * P + (mi + dx)) * 8;
        const f16x8 bf = *(const f16x8*)(w2frag + (size_t)(s * 64 + lane) * 8);
#pragma unroll
        for (int t = 0; t < 8; ++t) {
            f16x8 a = *(const f16x8*)(ap + t * 128);  // +t*16 voxels
            acc[t] = __builtin_amdgcn_mfma_f32_16x16x32_f16(a, bf, acc[t], 0, 0, 0);
        }
    }

    // C/D: col(oc)=mi, row(m)=q*4+r -> voxel w = 16t + q*4 + r
    const float bias = b2[mi];
    const size_t obase = ((size_t)(d0 + 1) * P + (h0 + 1)) * P + 1;
#pragma unroll
    for (int t = 0; t < 8; ++t) {
#pragma unroll
        for (int r = 0; r < 4; ++r) {
            float v = acc[t][r] + bias;
            v = v > 0.f ? v : 0.f;
            x2[(obase + 16 * t + q * 4 + r) * 16 + mi] = f2h(v);
        }
    }
}

// conv3: padded x2 [130^3][16] f16 -> out fp32 [128^3] (one batch), tanh.
// 8-voxel strip along h per thread (lanes consecutive in w -> coalesced).
// Position-major: per (dz, padded row r) load 3 dx-shifted chunks (6 b128, 96B)
// and consume immediately (up to 72 dot2), then the window dies.
// Issued bytes: 360 B/voxel (vs 864 at 1-vox/thread). 216 dot2/voxel exact.
__global__ __launch_bounds__(256) void conv3_kernel(
    const u16* __restrict__ x2, const unsigned* __restrict__ w3p,
    const float* __restrict__ b3, float* __restrict__ out) {
    const int t = blockIdx.x * 256 + threadIdx.x;  // VOX/8 threads
    const int w = t & 127;
    const int h0 = ((t >> 7) & 15) * 8;  // strip base (unpadded h)
    const int d = t >> 11;

    float accA[8], accB[8];
#pragma unroll
    for (int i = 0; i < 8; ++i) { accA[i] = 0.f; accB[i] = 0.f; }

#pragma unroll 1
    for (int dz = 0; dz < 3; ++dz) {
        // padded base of row r for this thread: (d+dz, h0+r, w)
        const u16* zb = x2 + ((size_t)((d + dz) * P + h0) * P + w) * 16;
        const unsigned* wz = w3p + dz * 9 * 8;
#pragma unroll
        for (int r = 0; r < 10; ++r) {
            const u16* rp = zb + (size_t)r * (P * 16);
            const uint4 c0l = *(const uint4*)(rp);
            const uint4 c0h = *(const uint4*)(rp + 8);
            const uint4 c1l = *(const uint4*)(rp + 16);
            const uint4 c1h = *(const uint4*)(rp + 24);
            const uint4 c2l = *(const uint4*)(rp + 32);
            const uint4 c2h = *(const uint4*)(rp + 40);
#pragma unroll
            for (int dy = 0; dy < 3; ++dy) {
                const int i = r - dy;
                if (i < 0 || i > 7) continue;  // compile-time after unroll
                const unsigned* wp = wz + dy * 3 * 8;
                float a = accA[i], b = accB[i];
                // dx=0 -> c0
                a = dot2(c0l.x, wp[0], a);  b = dot2(c0l.y, wp[1], b);
                a = dot2(c0l.z, wp[2], a);  b = dot2(c0l.w, wp[3], b);
                a = dot2(c0h.x, wp[4], a);  b = dot2(c0h.y, wp[5], b);
                a = dot2(c0h.z, wp[6], a);  b = dot2(c0h.w, wp[7], b);
                // dx=1 -> c1
                a = dot2(c1l.x, wp[8], a);  b = dot2(c1l.y, wp[9], b);
                a = dot2(c1l.z, wp[10], a); b = dot2(c1l.w, wp[11], b);
                a = dot2(c1h.x, wp[12], a); b = dot2(c1h.y, wp[13], b);
                a = dot2(c1h.z, wp[14], a); b = dot2(c1h.w, wp[15], b);
                // dx=2 -> c2
                a = dot2(c2l.x, wp[16], a); b = dot2(c2l.y, wp[17], b);
                a = dot2(c2l.z, wp[18], a); b = dot2(c2l.w, wp[19], b);
                a = dot2(c2h.x, wp[20], a); b = dot2(c2h.y, wp[21], b);
                a = dot2(c2h.z, wp[22], a); b = dot2(c2h.w, wp[23], b);
                accA[i] = a; accB[i] = b;
            }
        }
    }
    const float bias = b3[0];
    const size_t obase = (size_t)(d * 128 + h0) * 128 + w;
#pragma unroll
    for (int i = 0; i < 8; ++i)
        out[obase + (size_t)i * 128] = fast_tanh(accA[i] + accB[i] + bias);
}

extern "C" void kernel_launch(void* const* d_in, const int* in_sizes, int n_in,
                              void* d_out, int out_size, void* d_ws, size_t ws_size,
                              hipStream_t stream) {
    const float* cube = (const float*)d_in[0];
    const float* w1 = (const float*)d_in[1];
    const float* b1 = (const float*)d_in[2];
    const float* w2 = (const float*)d_in[3];
    const float* b2 = (const float*)d_in[4];
    const float* w3 = (const float*)d_in[5];
    const float* b3 = (const float*)d_in[6];
    float* out = (float*)d_out;

    // ws: w2frag 7168B | w3p 864B @7168 | w1p 864B @8032 | x1 @16384 | x2
    char* ws = (char*)d_ws;
    u16* w2frag = (u16*)ws;
    unsigned* w3p = (unsigned*)(ws + 7168);
    float2* w1p = (float2*)(ws + 8032);
    u16* x1 = (u16*)(ws + 16384);
    u16* x2 = (u16*)(ws + 16384 + (size_t)PVOX * 8 * sizeof(u16));

    prep_kernel<<<dim3(14), dim3(256), 0, stream>>>(w1, w2, w3, w2frag, w3p, w1p);
    zero_halo_kernel<<<dim3((PVOX + 255) / 256), dim3(256), 0, stream>>>(x1, x2);

    for (int b = 0; b < 2; ++b) {
        conv1_kernel<<<dim3(VOX / 2 / 256), dim3(256), 0, stream>>>(
            cube + (size_t)b * VOX, w1p, b1, x1);
        conv2_mfma_kernel<<<dim3(128 * 128 / 4), dim3(256), 0, stream>>>(x1, w2frag, b2, x2);
        conv3_kernel<<<dim3(VOX / 8 / 256), dim3(256), 0, stream>>>(
            x2, w3p, b3, out + (size_t)b * VOX);
    }
}

// Round 7
// 273.440 us; speedup vs baseline: 1.7055x; 1.1818x over previous
//
#include <hip/hip_runtime.h>
#include <hip/hip_fp16.h>

#define VOX (128 * 128 * 128)   // 2097152
#define P 130                   // padded dim
#define PP (P * P)              // 16900
#define PVOX (P * P * P)        // 2197000

typedef unsigned short u16;
typedef _Float16 f16x2 __attribute__((ext_vector_type(2)));
typedef _Float16 f16x8 __attribute__((ext_vector_type(8)));
typedef __attribute__((ext_vector_type(4))) float f32x4;
typedef __attribute__((ext_vector_type(2))) float f32x2;

__device__ __forceinline__ u16 f2h(float f) {
    return __builtin_bit_cast(unsigned short, (_Float16)f);
}
__device__ __forceinline__ unsigned pkh_relu(float a, float b) {
    float ra = a > 0.f ? a : 0.f, rb = b > 0.f ? b : 0.f;
    return (unsigned)f2h(ra) | ((unsigned)f2h(rb) << 16);
}
__device__ __forceinline__ f16x2 h2(unsigned u) { return __builtin_bit_cast(f16x2, u); }

// dot2: acc += a.x*b.x + a.y*b.y  (f32 accumulate, single V_DOT2_F32_F16)
__device__ __forceinline__ float dot2(unsigned a, unsigned b, float c) {
#if __has_builtin(__builtin_amdgcn_fdot2)
    return __builtin_amdgcn_fdot2(h2(a), h2(b), c, false);
#else
    f16x2 av = h2(a), bv = h2(b);
    c = fmaf((float)av.x, (float)bv.x, c);
    return fmaf((float)av.y, (float)bv.y, c);
#endif
}

// fast tanh: 1 - 2/(1+e^{2x})
__device__ __forceinline__ float fast_tanh(float x) {
    float e = __expf(2.0f * x);
    return 1.0f - 2.0f * __builtin_amdgcn_rcpf(1.0f + e);
}

// prep: w2frag[(s*64+lane)*8+j] = f16(w2[oc=lane&15][ic=j][tap=s*4+(lane>>4)]), 0 if tap>26
//       w3p[tap*8+j]  = packed f16 pair (w3[2j][tap], w3[2j+1][tap])
//       w1p[tap*4+j]  = float2 (w1[2j][tap], w1[2j+1][tap])
__global__ __launch_bounds__(256) void prep_kernel(
    const float* __restrict__ w1, const float* __restrict__ w2,
    const float* __restrict__ w3, u16* __restrict__ w2frag,
    unsigned* __restrict__ w3p, float2* __restrict__ w1p) {
    int i = blockIdx.x * 256 + threadIdx.x;
    if (i < 3584) {
        int j = i & 7, l = (i >> 3) & 63, s = i >> 9;
        int tap = s * 4 + (l >> 4), oc = l & 15, ic = j;
        float v = (tap < 27) ? w2[(oc * 8 + ic) * 27 + tap] : 0.0f;
        w2frag[i] = f2h(v);
    }
    if (i < 216) {
        int tap = i >> 3, j = i & 7;
        w3p[i] = (unsigned)f2h(w3[(2 * j) * 27 + tap]) |
                 ((unsigned)f2h(w3[(2 * j + 1) * 27 + tap]) << 16);
    }
    if (i < 108) {
        int tap = i >> 2, j = i & 3;
        w1p[i] = make_float2(w1[(2 * j) * 27 + tap], w1[(2 * j + 1) * 27 + tap]);
    }
}

// zero the halo shells of padded x1 (8ch) and x2 (16ch)
__global__ __launch_bounds__(256) void zero_halo_kernel(u16* __restrict__ x1,
                                                        u16* __restrict__ x2) {
    int i = blockIdx.x * 256 + threadIdx.x;
    if (i >= PVOX) return;
    int d = i / PP;
    int r = i - d * PP;
    int h = r / P;
    int w = r - h * P;
    if (d == 0 || d == P - 1 || h == 0 || h == P - 1 || w == 0 || w == P - 1) {
        uint4 z = {0u, 0u, 0u, 0u};
        *(uint4*)(x1 + (size_t)i * 8) = z;
        *(uint4*)(x2 + (size_t)i * 16) = z;
        *(uint4*)(x2 + (size_t)i * 16 + 8) = z;
    }
}

// integrate: x0 padded f16 [130^3] = cube * (1 + 0.1*sin(2pi*(d+h+w)/384)), halo = 0
__global__ __launch_bounds__(256) void integrate_kernel(
    const float* __restrict__ in, u16* __restrict__ x0) {
    int i = blockIdx.x * 256 + threadIdx.x;
    if (i >= PVOX) return;
    int d = i / PP;
    int r = i - d * PP;
    int h = r / P;
    int w = r - h * P;
    float v = 0.0f;
    if (d >= 1 && d <= 128 && h >= 1 && h <= 128 && w >= 1 && w <= 128) {
        int s = (d - 1) + (h - 1) + (w - 1);
        float fld = 1.0f + 0.1f * sinf(6.283185307179586f * (float)s / 384.0f);
        v = in[(size_t)(d - 1) * 16384 + (h - 1) * 128 + (w - 1)] * fld;
    }
    x0[i] = f2h(v);
}

// conv1: x0 padded f16 [130^3] -> x1 f16 channels-last padded [130^3][8], relu.
// Strip 4(h) x 2(w) voxels/thread; per (dz, r in 0..5): one 4-f16 window load,
// zero boundary logic. 864 pk_fma/thread; acc = 64 VGPRs, short load liveness.
__global__ __launch_bounds__(256) void conv1_kernel(
    const u16* __restrict__ x0, const float2* __restrict__ w1p,
    const float* __restrict__ b1, u16* __restrict__ x1) {
    const int t = blockIdx.x * 256 + threadIdx.x;  // VOX/8 threads
    const int w0 = (t & 63) * 2;
    const int h0 = ((t >> 6) & 31) * 4;
    const int d = t >> 11;

    f32x2 acc[4][4][2];  // [i][jpair][vox]
#pragma unroll
    for (int j = 0; j < 4; ++j) {
        const f32x2 b = {b1[2 * j], b1[2 * j + 1]};
#pragma unroll
        for (int i = 0; i < 4; ++i) { acc[i][j][0] = b; acc[i][j][1] = b; }
    }

#pragma unroll
    for (int dz = 0; dz < 3; ++dz) {
        // padded row (d+dz, h0+r, w0..w0+3); padded (pd,ph,pw) = voxel (pd-1,ph-1,pw-1)
        const u16* zb = x0 + (size_t)(d + dz) * PP + (size_t)h0 * P + w0;
        const float2* wz = w1p + dz * 9 * 4;
#pragma unroll
        for (int r = 0; r < 6; ++r) {
            const u16* rp = zb + r * P;
            const unsigned u0 = *(const unsigned*)rp;
            const unsigned u1 = *(const unsigned*)(rp + 2);
            float vv[4];
            vv[0] = (float)h2(u0).x; vv[1] = (float)h2(u0).y;
            vv[2] = (float)h2(u1).x; vv[3] = (float)h2(u1).y;
#pragma unroll
            for (int dy = 0; dy < 3; ++dy) {
                const int i = r - dy;
                if (i < 0 || i > 3) continue;  // resolved at compile time
#pragma unroll
                for (int dx = 0; dx < 3; ++dx) {
                    const f32x2 s0 = {vv[dx], vv[dx]};
                    const f32x2 s1 = {vv[dx + 1], vv[dx + 1]};
#pragma unroll
                    for (int j = 0; j < 4; ++j) {
                        const float2 wraw = wz[(dy * 3 + dx) * 4 + j];
                        const f32x2 wv = {wraw.x, wraw.y};
                        acc[i][j][0] = __builtin_elementwise_fma(wv, s0, acc[i][j][0]);
                        acc[i][j][1] = __builtin_elementwise_fma(wv, s1, acc[i][j][1]);
                    }
                }
            }
        }
    }
    const size_t e0 = ((size_t)(d + 1) * P + (h0 + 1)) * P + (w0 + 1);
#pragma unroll
    for (int i = 0; i < 4; ++i) {
        uint4 oA, oB;
        oA.x = pkh_relu(acc[i][0][0].x, acc[i][0][0].y);
        oA.y = pkh_relu(acc[i][1][0].x, acc[i][1][0].y);
        oA.z = pkh_relu(acc[i][2][0].x, acc[i][2][0].y);
        oA.w = pkh_relu(acc[i][3][0].x, acc[i][3][0].y);
        oB.x = pkh_relu(acc[i][0][1].x, acc[i][0][1].y);
        oB.y = pkh_relu(acc[i][1][1].x, acc[i][1][1].y);
        oB.z = pkh_relu(acc[i][2][1].x, acc[i][2][1].y);
        oB.w = pkh_relu(acc[i][3][1].x, acc[i][3][1].y);
        *(uint4*)(x1 + (e0 + (size_t)i * P) * 8) = oA;
        *(uint4*)(x1 + (e0 + (size_t)i * P + 1) * 8) = oB;
    }
}

// conv2: implicit-GEMM MFMA (f16), padded layouts, no boundary logic.
// One wave = one (d,h) row = 8 tiles of 16 voxels; 7 k-steps; 56 MFMAs/wave.
__global__ __launch_bounds__(256) void conv2_mfma_kernel(
    const u16* __restrict__ x1, const u16* __restrict__ w2frag,
    const float* __restrict__ b2, u16* __restrict__ x2) {
    const int lane = threadIdx.x & 63;
    const int row = blockIdx.x * 4 + (threadIdx.x >> 6);
    const int q = lane >> 4;
    const int mi = lane & 15;
    const int d0 = row >> 7;
    const int h0 = row & 127;

    f32x4 acc[8];
#pragma unroll
    for (int t = 0; t < 8; ++t) acc[t] = (f32x4){0.f, 0.f, 0.f, 0.f};

#pragma unroll
    for (int s = 0; s < 7; ++s) {
        int tap = s * 4 + q;
        if (tap > 26) tap = 26;  // pad tap: B-frag is zero there
        const int dz = tap / 9;
        const int rem = tap - dz * 9;
        const int dy = rem / 3;
        const int dx = rem - dy * 3;
        const u16* ap = x1 + ((size_t)((d0 + dz) * P + (h0 + dy)) * P + (mi + dx)) * 8;
        const f16x8 bf = *(const f16x8*)(w2frag + (size_t)(s * 64 + lane) * 8);
#pragma unroll
        for (int t = 0; t < 8; ++t) {
            f16x8 a = *(const f16x8*)(ap + t * 128);  // +t*16 voxels
            acc[t] = __builtin_amdgcn_mfma_f32_16x16x32_f16(a, bf, acc[t], 0, 0, 0);
        }
    }

    // C/D: col(oc)=mi, row(m)=q*4+r -> voxel w = 16t + q*4 + r
    const float bias = b2[mi];
    const size_t obase = ((size_t)(d0 + 1) * P + (h0 + 1)) * P + 1;
#pragma unroll
    for (int t = 0; t < 8; ++t) {
#pragma unroll
        for (int r = 0; r < 4; ++r) {
            float v = acc[t][r] + bias;
            v = v > 0.f ? v : 0.f;
            x2[(obase + 16 * t + q * 4 + r) * 16 + mi] = f2h(v);
        }
    }
}

// conv3: padded x2 [130^3][16] f16 -> out fp32 [128^3] (one batch), tanh.
// 8-voxel strip along h per thread; position-major immediate consumption.
__global__ __launch_bounds__(256) void conv3_kernel(
    const u16* __restrict__ x2, const unsigned* __restrict__ w3p,
    const float* __restrict__ b3, float* __restrict__ out) {
    const int t = blockIdx.x * 256 + threadIdx.x;  // VOX/8 threads
    const int w = t & 127;
    const int h0 = ((t >> 7) & 15) * 8;  // strip base (unpadded h)
    const int d = t >> 11;

    float accA[8], accB[8];
#pragma unroll
    for (int i = 0; i < 8; ++i) { accA[i] = 0.f; accB[i] = 0.f; }

#pragma unroll 1
    for (int dz = 0; dz < 3; ++dz) {
        const u16* zb = x2 + ((size_t)((d + dz) * P + h0) * P + w) * 16;
        const unsigned* wz = w3p + dz * 9 * 8;
#pragma unroll
        for (int r = 0; r < 10; ++r) {
            const u16* rp = zb + (size_t)r * (P * 16);
            const uint4 c0l = *(const uint4*)(rp);
            const uint4 c0h = *(const uint4*)(rp + 8);
            const uint4 c1l = *(const uint4*)(rp + 16);
            const uint4 c1h = *(const uint4*)(rp + 24);
            const uint4 c2l = *(const uint4*)(rp + 32);
            const uint4 c2h = *(const uint4*)(rp + 40);
#pragma unroll
            for (int dy = 0; dy < 3; ++dy) {
                const int i = r - dy;
                if (i < 0 || i > 7) continue;  // compile-time after unroll
                const unsigned* wp = wz + dy * 3 * 8;
                float a = accA[i], b = accB[i];
                a = dot2(c0l.x, wp[0], a);  b = dot2(c0l.y, wp[1], b);
                a = dot2(c0l.z, wp[2], a);  b = dot2(c0l.w, wp[3], b);
                a = dot2(c0h.x, wp[4], a);  b = dot2(c0h.y, wp[5], b);
                a = dot2(c0h.z, wp[6], a);  b = dot2(c0h.w, wp[7], b);
                a = dot2(c1l.x, wp[8], a);  b = dot2(c1l.y, wp[9], b);
                a = dot2(c1l.z, wp[10], a); b = dot2(c1l.w, wp[11], b);
                a = dot2(c1h.x, wp[12], a); b = dot2(c1h.y, wp[13], b);
                a = dot2(c1h.z, wp[14], a); b = dot2(c1h.w, wp[15], b);
                a = dot2(c2l.x, wp[16], a); b = dot2(c2l.y, wp[17], b);
                a = dot2(c2l.z, wp[18], a); b = dot2(c2l.w, wp[19], b);
                a = dot2(c2h.x, wp[20], a); b = dot2(c2h.y, wp[21], b);
                a = dot2(c2h.z, wp[22], a); b = dot2(c2h.w, wp[23], b);
                accA[i] = a; accB[i] = b;
            }
        }
    }
    const float bias = b3[0];
    const size_t obase = (size_t)(d * 128 + h0) * 128 + w;
#pragma unroll
    for (int i = 0; i < 8; ++i)
        out[obase + (size_t)i * 128] = fast_tanh(accA[i] + accB[i] + bias);
}

extern "C" void kernel_launch(void* const* d_in, const int* in_sizes, int n_in,
                              void* d_out, int out_size, void* d_ws, size_t ws_size,
                              hipStream_t stream) {
    const float* cube = (const float*)d_in[0];
    const float* w1 = (const float*)d_in[1];
    const float* b1 = (const float*)d_in[2];
    const float* w2 = (const float*)d_in[3];
    const float* b2 = (const float*)d_in[4];
    const float* w3 = (const float*)d_in[5];
    const float* b3 = (const float*)d_in[6];
    float* out = (float*)d_out;

    // ws: w2frag@0 | w3p@7168 | w1p@8032 | x0 f16 PVOX @16384 | x1 | x2  (~105 MB)
    char* ws = (char*)d_ws;
    u16* w2frag = (u16*)ws;
    unsigned* w3p = (unsigned*)(ws + 7168);
    float2* w1p = (float2*)(ws + 8032);
    u16* x0 = (u16*)(ws + 16384);
    u16* x1 = (u16*)(ws + 16384 + (size_t)PVOX * sizeof(u16));
    u16* x2 = (u16*)(ws + 16384 + (size_t)PVOX * sizeof(u16) + (size_t)PVOX * 8 * sizeof(u16));

    prep_kernel<<<dim3(14), dim3(256), 0, stream>>>(w1, w2, w3, w2frag, w3p, w1p);
    zero_halo_kernel<<<dim3((PVOX + 255) / 256), dim3(256), 0, stream>>>(x1, x2);

    for (int b = 0; b < 2; ++b) {
        integrate_kernel<<<dim3((PVOX + 255) / 256), dim3(256), 0, stream>>>(
            cube + (size_t)b * VOX, x0);
        conv1_kernel<<<dim3(VOX / 8 / 256), dim3(256), 0, stream>>>(x0, w1p, b1, x1);
        conv2_mfma_kernel<<<dim3(128 * 128 / 4), dim3(256), 0, stream>>>(x1, w2frag, b2, x2);
        conv3_kernel<<<dim3(VOX / 8 / 256), dim3(256), 0, stream>>>(
            x2, w3p, b3, out + (size_t)b * VOX);
    }
}

// Round 8
// 264.024 us; speedup vs baseline: 1.7664x; 1.0357x over previous
//
#include <hip/hip_runtime.h>
#include <hip/hip_fp16.h>

#define VOX (128 * 128 * 128)   // 2097152
#define P 130                   // padded dim
#define PP (P * P)              // 16900
#define PVOX (P * P * P)        // 2197000

typedef unsigned short u16;
typedef _Float16 f16x2 __attribute__((ext_vector_type(2)));
typedef _Float16 f16x8 __attribute__((ext_vector_type(8)));
typedef __attribute__((ext_vector_type(4))) float f32x4;
typedef __attribute__((ext_vector_type(2))) float f32x2;

__device__ __forceinline__ u16 f2h(float f) {
    return __builtin_bit_cast(unsigned short, (_Float16)f);
}
__device__ __forceinline__ unsigned pkh_relu(float a, float b) {
    float ra = a > 0.f ? a : 0.f, rb = b > 0.f ? b : 0.f;
    return (unsigned)f2h(ra) | ((unsigned)f2h(rb) << 16);
}
__device__ __forceinline__ f16x2 h2(unsigned u) { return __builtin_bit_cast(f16x2, u); }

// dot2: acc += a.x*b.x + a.y*b.y  (f32 accumulate, single V_DOT2_F32_F16)
__device__ __forceinline__ float dot2(unsigned a, unsigned b, float c) {
#if __has_builtin(__builtin_amdgcn_fdot2)
    return __builtin_amdgcn_fdot2(h2(a), h2(b), c, false);
#else
    f16x2 av = h2(a), bv = h2(b);
    c = fmaf((float)av.x, (float)bv.x, c);
    return fmaf((float)av.y, (float)bv.y, c);
#endif
}

// fast tanh: 1 - 2/(1+e^{2x})
__device__ __forceinline__ float fast_tanh(float x) {
    float e = __expf(2.0f * x);
    return 1.0f - 2.0f * __builtin_amdgcn_rcpf(1.0f + e);
}

// prep: w2frag[(s*64+lane)*8+j] = f16(w2[oc=lane&15][ic=j][tap=s*4+(lane>>4)]), 0 if tap>26
//       w3p[tap*8+j]  = packed f16 pair (w3[2j][tap], w3[2j+1][tap])
//       w1p[tap*4+j]  = float2 (w1[2j][tap], w1[2j+1][tap])
__global__ __launch_bounds__(256) void prep_kernel(
    const float* __restrict__ w1, const float* __restrict__ w2,
    const float* __restrict__ w3, u16* __restrict__ w2frag,
    unsigned* __restrict__ w3p, float2* __restrict__ w1p) {
    int i = blockIdx.x * 256 + threadIdx.x;
    if (i < 3584) {
        int j = i & 7, l = (i >> 3) & 63, s = i >> 9;
        int tap = s * 4 + (l >> 4), oc = l & 15, ic = j;
        float v = (tap < 27) ? w2[(oc * 8 + ic) * 27 + tap] : 0.0f;
        w2frag[i] = f2h(v);
    }
    if (i < 216) {
        int tap = i >> 3, j = i & 7;
        w3p[i] = (unsigned)f2h(w3[(2 * j) * 27 + tap]) |
                 ((unsigned)f2h(w3[(2 * j + 1) * 27 + tap]) << 16);
    }
    if (i < 108) {
        int tap = i >> 2, j = i & 3;
        w1p[i] = make_float2(w1[(2 * j) * 27 + tap], w1[(2 * j + 1) * 27 + tap]);
    }
}

// zero the halo shells of padded x1 (8ch) and x2 (16ch)
__global__ __launch_bounds__(256) void zero_halo_kernel(u16* __restrict__ x1,
                                                        u16* __restrict__ x2) {
    int i = blockIdx.x * 256 + threadIdx.x;
    if (i >= PVOX) return;
    int d = i / PP;
    int r = i - d * PP;
    int h = r / P;
    int w = r - h * P;
    if (d == 0 || d == P - 1 || h == 0 || h == P - 1 || w == 0 || w == P - 1) {
        uint4 z = {0u, 0u, 0u, 0u};
        *(uint4*)(x1 + (size_t)i * 8) = z;
        *(uint4*)(x2 + (size_t)i * 16) = z;
        *(uint4*)(x2 + (size_t)i * 16 + 8) = z;
    }
}

// integrate: x0 padded f16 [130^3] = cube * (1 + 0.1*sin(2pi*(d+h+w)/384)), halo = 0
__global__ __launch_bounds__(256) void integrate_kernel(
    const float* __restrict__ in, u16* __restrict__ x0) {
    int i = blockIdx.x * 256 + threadIdx.x;
    if (i >= PVOX) return;
    int d = i / PP;
    int r = i - d * PP;
    int h = r / P;
    int w = r - h * P;
    float v = 0.0f;
    if (d >= 1 && d <= 128 && h >= 1 && h <= 128 && w >= 1 && w <= 128) {
        int s = (d - 1) + (h - 1) + (w - 1);
        float fld = 1.0f + 0.1f * sinf(6.283185307179586f * (float)s / 384.0f);
        v = in[(size_t)(d - 1) * 16384 + (h - 1) * 128 + (w - 1)] * fld;
    }
    x0[i] = f2h(v);
}

// conv1: x0 padded f16 [130^3] -> x1 f16 channels-last padded [130^3][8], relu.
// Strip 4(h) x 2(w) voxels/thread; per (dz, r in 0..5): one 4-f16 window load,
// zero boundary logic. 864 pk_fma/thread; acc = 64 VGPRs, short load liveness.
__global__ __launch_bounds__(256) void conv1_kernel(
    const u16* __restrict__ x0, const float2* __restrict__ w1p,
    const float* __restrict__ b1, u16* __restrict__ x1) {
    const int t = blockIdx.x * 256 + threadIdx.x;  // VOX/8 threads
    const int w0 = (t & 63) * 2;
    const int h0 = ((t >> 6) & 31) * 4;
    const int d = t >> 11;

    f32x2 acc[4][4][2];  // [i][jpair][vox]
#pragma unroll
    for (int j = 0; j < 4; ++j) {
        const f32x2 b = {b1[2 * j], b1[2 * j + 1]};
#pragma unroll
        for (int i = 0; i < 4; ++i) { acc[i][j][0] = b; acc[i][j][1] = b; }
    }

#pragma unroll
    for (int dz = 0; dz < 3; ++dz) {
        const u16* zb = x0 + (size_t)(d + dz) * PP + (size_t)h0 * P + w0;
        const float2* wz = w1p + dz * 9 * 4;
#pragma unroll
        for (int r = 0; r < 6; ++r) {
            const u16* rp = zb + r * P;
            const unsigned u0 = *(const unsigned*)rp;
            const unsigned u1 = *(const unsigned*)(rp + 2);
            float vv[4];
            vv[0] = (float)h2(u0).x; vv[1] = (float)h2(u0).y;
            vv[2] = (float)h2(u1).x; vv[3] = (float)h2(u1).y;
#pragma unroll
            for (int dy = 0; dy < 3; ++dy) {
                const int i = r - dy;
                if (i < 0 || i > 3) continue;  // resolved at compile time
#pragma unroll
                for (int dx = 0; dx < 3; ++dx) {
                    const f32x2 s0 = {vv[dx], vv[dx]};
                    const f32x2 s1 = {vv[dx + 1], vv[dx + 1]};
#pragma unroll
                    for (int j = 0; j < 4; ++j) {
                        const float2 wraw = wz[(dy * 3 + dx) * 4 + j];
                        const f32x2 wv = {wraw.x, wraw.y};
                        acc[i][j][0] = __builtin_elementwise_fma(wv, s0, acc[i][j][0]);
                        acc[i][j][1] = __builtin_elementwise_fma(wv, s1, acc[i][j][1]);
                    }
                }
            }
        }
    }
    const size_t e0 = ((size_t)(d + 1) * P + (h0 + 1)) * P + (w0 + 1);
#pragma unroll
    for (int i = 0; i < 4; ++i) {
        uint4 oA, oB;
        oA.x = pkh_relu(acc[i][0][0].x, acc[i][0][0].y);
        oA.y = pkh_relu(acc[i][1][0].x, acc[i][1][0].y);
        oA.z = pkh_relu(acc[i][2][0].x, acc[i][2][0].y);
        oA.w = pkh_relu(acc[i][3][0].x, acc[i][3][0].y);
        oB.x = pkh_relu(acc[i][0][1].x, acc[i][0][1].y);
        oB.y = pkh_relu(acc[i][1][1].x, acc[i][1][1].y);
        oB.z = pkh_relu(acc[i][2][1].x, acc[i][2][1].y);
        oB.w = pkh_relu(acc[i][3][1].x, acc[i][3][1].y);
        *(uint4*)(x1 + (e0 + (size_t)i * P) * 8) = oA;
        *(uint4*)(x1 + (e0 + (size_t)i * P + 1) * 8) = oB;
    }
}

// conv2: implicit-GEMM MFMA (f16), padded layouts, no boundary logic.
// TRANSPOSED orientation: A = weights (M=16 oc), B = activations (N=16 voxels).
// A/B fragment layouts are symmetric, so both loads are unchanged from the
// previous orientation; only mfma operand order and the epilogue differ.
// D: row(m)=q*4+r = oc, col(n)=mi = voxel -> lane holds 4 consecutive channels
// of ONE voxel = 8 contiguous bytes -> single dwordx2 store per tile; a wave
// store covers a dense 512B region (16 vox x 32B). Was: 4 scattered b16/lane.
__global__ __launch_bounds__(256) void conv2_mfma_kernel(
    const u16* __restrict__ x1, const u16* __restrict__ w2frag,
    const float* __restrict__ b2, u16* __restrict__ x2) {
    const int lane = threadIdx.x & 63;
    const int row = blockIdx.x * 4 + (threadIdx.x >> 6);
    const int q = lane >> 4;
    const int mi = lane & 15;
    const int d0 = row >> 7;
    const int h0 = row & 127;

    f32x4 acc[8];
#pragma unroll
    for (int t = 0; t < 8; ++t) acc[t] = (f32x4){0.f, 0.f, 0.f, 0.f};

#pragma unroll
    for (int s = 0; s < 7; ++s) {
        int tap = s * 4 + q;
        if (tap > 26) tap = 26;  // pad tap: A-frag (weights) is zero there
        const int dz = tap / 9;
        const int rem = tap - dz * 9;
        const int dy = rem / 3;
        const int dx = rem - dy * 3;
        const u16* bp = x1 + ((size_t)((d0 + dz) * P + (h0 + dy)) * P + (mi + dx)) * 8;
        const f16x8 wf = *(const f16x8*)(w2frag + (size_t)(s * 64 + lane) * 8);
#pragma unroll
        for (int t = 0; t < 8; ++t) {
            f16x8 act = *(const f16x8*)(bp + t * 128);  // +t*16 voxels
            acc[t] = __builtin_amdgcn_mfma_f32_16x16x32_f16(wf, act, acc[t], 0, 0, 0);
        }
    }

    // D: row(oc)=q*4+r, col(voxel)=mi
    const float4 bv = *(const float4*)(b2 + q * 4);
    const size_t obase = ((size_t)(d0 + 1) * P + (h0 + 1)) * P + 1;
#pragma unroll
    for (int t = 0; t < 8; ++t) {
        const float v0 = acc[t][0] + bv.x;
        const float v1 = acc[t][1] + bv.y;
        const float v2 = acc[t][2] + bv.z;
        const float v3 = acc[t][3] + bv.w;
        uint2 o;
        o.x = pkh_relu(v0, v1);
        o.y = pkh_relu(v2, v3);
        *(uint2*)(x2 + (obase + 16 * t + mi) * 16 + q * 4) = o;
    }
}

// conv3: padded x2 [130^3][16] f16 -> out fp32 [128^3] (one batch), tanh.
// 8-voxel strip along h per thread; position-major immediate consumption.
__global__ __launch_bounds__(256) void conv3_kernel(
    const u16* __restrict__ x2, const unsigned* __restrict__ w3p,
    const float* __restrict__ b3, float* __restrict__ out) {
    const int t = blockIdx.x * 256 + threadIdx.x;  // VOX/8 threads
    const int w = t & 127;
    const int h0 = ((t >> 7) & 15) * 8;  // strip base (unpadded h)
    const int d = t >> 11;

    float accA[8], accB[8];
#pragma unroll
    for (int i = 0; i < 8; ++i) { accA[i] = 0.f; accB[i] = 0.f; }

#pragma unroll 1
    for (int dz = 0; dz < 3; ++dz) {
        const u16* zb = x2 + ((size_t)((d + dz) * P + h0) * P + w) * 16;
        const unsigned* wz = w3p + dz * 9 * 8;
#pragma unroll
        for (int r = 0; r < 10; ++r) {
            const u16* rp = zb + (size_t)r * (P * 16);
            const uint4 c0l = *(const uint4*)(rp);
            const uint4 c0h = *(const uint4*)(rp + 8);
            const uint4 c1l = *(const uint4*)(rp + 16);
            const uint4 c1h = *(const uint4*)(rp + 24);
            const uint4 c2l = *(const uint4*)(rp + 32);
            const uint4 c2h = *(const uint4*)(rp + 40);
#pragma unroll
            for (int dy = 0; dy < 3; ++dy) {
                const int i = r - dy;
                if (i < 0 || i > 7) continue;  // compile-time after unroll
                const unsigned* wp = wz + dy * 3 * 8;
                float a = accA[i], b = accB[i];
                a = dot2(c0l.x, wp[0], a);  b = dot2(c0l.y, wp[1], b);
                a = dot2(c0l.z, wp[2], a);  b = dot2(c0l.w, wp[3], b);
                a = dot2(c0h.x, wp[4], a);  b = dot2(c0h.y, wp[5], b);
                a = dot2(c0h.z, wp[6], a);  b = dot2(c0h.w, wp[7], b);
                a = dot2(c1l.x, wp[8], a);  b = dot2(c1l.y, wp[9], b);
                a = dot2(c1l.z, wp[10], a); b = dot2(c1l.w, wp[11], b);
                a = dot2(c1h.x, wp[12], a); b = dot2(c1h.y, wp[13], b);
                a = dot2(c1h.z, wp[14], a); b = dot2(c1h.w, wp[15], b);
                a = dot2(c2l.x, wp[16], a); b = dot2(c2l.y, wp[17], b);
                a = dot2(c2l.z, wp[18], a); b = dot2(c2l.w, wp[19], b);
                a = dot2(c2h.x, wp[20], a); b = dot2(c2h.y, wp[21], b);
                a = dot2(c2h.z, wp[22], a); b = dot2(c2h.w, wp[23], b);
                accA[i] = a; accB[i] = b;
            }
        }
    }
    const float bias = b3[0];
    const size_t obase = (size_t)(d * 128 + h0) * 128 + w;
#pragma unroll
    for (int i = 0; i < 8; ++i)
        out[obase + (size_t)i * 128] = fast_tanh(accA[i] + accB[i] + bias);
}

extern "C" void kernel_launch(void* const* d_in, const int* in_sizes, int n_in,
                              void* d_out, int out_size, void* d_ws, size_t ws_size,
                              hipStream_t stream) {
    const float* cube = (const float*)d_in[0];
    const float* w1 = (const float*)d_in[1];
    const float* b1 = (const float*)d_in[2];
    const float* w2 = (const float*)d_in[3];
    const float* b2 = (const float*)d_in[4];
    const float* w3 = (const float*)d_in[5];
    const float* b3 = (const float*)d_in[6];
    float* out = (float*)d_out;

    // ws: w2frag@0 | w3p@7168 | w1p@8032 | x0 f16 PVOX @16384 | x1 | x2  (~105 MB)
    char* ws = (char*)d_ws;
    u16* w2frag = (u16*)ws;
    unsigned* w3p = (unsigned*)(ws + 7168);
    float2* w1p = (float2*)(ws + 8032);
    u16* x0 = (u16*)(ws + 16384);
    u16* x1 = (u16*)(ws + 16384 + (size_t)PVOX * sizeof(u16));
    u16* x2 = (u16*)(ws + 16384 + (size_t)PVOX * sizeof(u16) + (size_t)PVOX * 8 * sizeof(u16));

    prep_kernel<<<dim3(14), dim3(256), 0, stream>>>(w1, w2, w3, w2frag, w3p, w1p);
    zero_halo_kernel<<<dim3((PVOX + 255) / 256), dim3(256), 0, stream>>>(x1, x2);

    for (int b = 0; b < 2; ++b) {
        integrate_kernel<<<dim3((PVOX + 255) / 256), dim3(256), 0, stream>>>(
            cube + (size_t)b * VOX, x0);
        conv1_kernel<<<dim3(VOX / 8 / 256), dim3(256), 0, stream>>>(x0, w1p, b1, x1);
        conv2_mfma_kernel<<<dim3(128 * 128 / 4), dim3(256), 0, stream>>>(x1, w2frag, b2, x2);
        conv3_kernel<<<dim3(VOX / 8 / 256), dim3(256), 0, stream>>>(
            x2, w3p, b3, out + (size_t)b * VOX);
    }
}